// Round 1
// baseline (43.322 us; speedup 1.0000x reference)
//
#include <hip/hip_runtime.h>
#include <math.h>

#define NBATCH 2048
#define GS 14
#define NCELL (GS * GS)      // 196
#define NCH 30
#define MAXOBJ 20
#define NCLS 20
#define PSTRIDE 33           // LDS stride per cell (avoid bank conflicts)

// ---------------------------------------------------------------------------
// Kernel 1: one block per batch element. Builds the conf/cls targets in LDS
// (sequential 20-object loop, last-write-wins) then reduces the per-cell loss
// contributions to 7 partial sums per block.
// partials[b*8 + k]: 0=s_noobj 1=c_noobj 2=s_objconf 3=s_xy 4=s_wh 5=s_clc 6=c_obj
// ---------------------------------------------------------------------------
__global__ __launch_bounds__(256) void yolo_partial_kernel(
        const float* __restrict__ pred,
        const float* __restrict__ target,
        float* __restrict__ partials)
{
    __shared__ float s_pred[NCELL * PSTRIDE];     // 25872 B
    __shared__ float s_tgt[MAXOBJ * 5];           // 400 B
    __shared__ float s_box[2][NCELL][4];          // offx,offy,w,h
    __shared__ unsigned char s_flag[2][NCELL];
    __shared__ unsigned int s_clsmask[NCELL];
    __shared__ float s_red[4][8];

    const int b = blockIdx.x;
    const int tid = threadIdx.x;

    // ---- stage pred slab (5880 f32) into LDS, stride-33 per cell ----
    const float* ps = pred + (size_t)b * (NCELL * NCH);
    for (int i = tid; i < NCELL * NCH; i += 256) {
        int cell = i / NCH;
        int c = i - cell * NCH;
        s_pred[cell * PSTRIDE + c] = ps[i];
    }
    // ---- stage target row ----
    const float* ts = target + (size_t)b * (MAXOBJ * 5);
    if (tid < MAXOBJ * 5) s_tgt[tid] = ts[tid];
    // ---- zero target-state arrays ----
    if (tid < NCELL) {
        s_flag[0][tid] = 0;
        s_flag[1][tid] = 0;
        s_clsmask[tid] = 0u;
    }
    __syncthreads();

    // ---- sequential object loop (last-write-wins semantics) ----
    if (tid == 0) {
        const float fg = (float)GS;
        for (int o = 0; o < MAXOBJ; ++o) {
            float x1 = s_tgt[o * 5 + 0];
            float y1 = s_tgt[o * 5 + 1];
            float x2 = s_tgt[o * 5 + 2];
            float y2 = s_tgt[o * 5 + 3];
            float cf = s_tgt[o * 5 + 4];
            if (x1 + y1 + x2 + y2 + cf == 0.0f) continue;  // invalid slot

            float cx = (x1 + x2) * 0.5f * fg;
            float cy = (y1 + y2) * 0.5f * fg;
            float w = x2 - x1;
            float h = y2 - y1;
            int gx = (int)floorf(cx); gx = min(max(gx, 0), GS - 1);
            int gy = (int)floorf(cy); gy = min(max(gy, 0), GS - 1);
            float offx = cx - (float)gx;
            float offy = cy - (float)gy;
            int cell = gy * GS + gx;
            const float* pc = &s_pred[cell * PSTRIDE];

            // target box in normalized coords (center = off/fg, size = w,h)
            float tcx = offx / fg, tcy = offy / fg;
            float tl_x = tcx - 0.5f * w, tl_y = tcy - 0.5f * h;
            float tr_x = tcx + 0.5f * w, tr_y = tcy + 0.5f * h;
            float t_area = (tr_x - tl_x) * (tr_y - tl_y);

            float iou0 = 0.0f, iou1 = 0.0f;
            #pragma unroll
            for (int k = 0; k < 2; ++k) {
                float px = pc[k * 5 + 1] / fg;
                float py = pc[k * 5 + 2] / fg;
                float pw = pc[k * 5 + 3];
                float ph = pc[k * 5 + 4];
                float pl_x = px - 0.5f * pw, pl_y = py - 0.5f * ph;
                float pr_x = px + 0.5f * pw, pr_y = py + 0.5f * ph;
                float ix = fminf(pr_x, tr_x) - fmaxf(pl_x, tl_x);
                float iy = fminf(pr_y, tr_y) - fmaxf(pl_y, tl_y);
                ix = fmaxf(ix, 0.0f);
                iy = fmaxf(iy, 0.0f);
                float inter = ix * iy;
                float a1 = (pr_x - pl_x) * (pr_y - pl_y);
                float iou = inter / (a1 + t_area - inter);
                if (k == 0) iou0 = iou; else iou1 = iou;
            }
            int mi = (iou1 > iou0) ? 1 : 0;  // argmax, first-wins on tie

            s_flag[mi][cell] = 1;
            s_box[mi][cell][0] = offx;
            s_box[mi][cell][1] = offy;
            s_box[mi][cell][2] = w;
            s_box[mi][cell][3] = h;
            s_clsmask[cell] |= (1u << (int)cf);
        }
    }
    __syncthreads();

    // ---- per-cell loss partials ----
    float v_noobj = 0.f, v_cnoobj = 0.f, v_objconf = 0.f;
    float v_xy = 0.f, v_wh = 0.f, v_clc = 0.f, v_cobj = 0.f;
    for (int cell = tid; cell < NCELL; cell += 256) {
        const float* pc = &s_pred[cell * PSTRIDE];
        int f0 = s_flag[0][cell];
        int f1 = s_flag[1][cell];
        int nset = f0 + f1;
        if (nset == 0) {
            float c0 = pc[0];
            float c1 = pc[5];
            v_noobj += c0 * c0 + c1 * c1;
            v_cnoobj += 1.0f;
        } else if (nset == 1) {
            int k = f1;  // set box index
            float conf = pc[k * 5 + 0];
            float dconf = conf - 1.0f;
            v_objconf += dconf * dconf;
            float dx = pc[k * 5 + 1] - s_box[k][cell][0];
            float dy = pc[k * 5 + 2] - s_box[k][cell][1];
            v_xy += dx * dx + dy * dy;
            float sw = sqrtf(pc[k * 5 + 3]) - sqrtf(s_box[k][cell][2]);
            float sh = sqrtf(pc[k * 5 + 4]) - sqrtf(s_box[k][cell][3]);
            v_wh += sw * sw + sh * sh;
            unsigned int m = s_clsmask[cell];
            #pragma unroll
            for (int c = 0; c < NCLS; ++c) {
                float t = ((m >> c) & 1u) ? 1.0f : 0.0f;
                float d = pc[10 + c] - t;
                v_clc += d * d;
            }
            v_cobj += 1.0f;
        }
        // nset == 2: excluded from every loss term
    }

    // ---- wave reduce (64 lanes) then cross-wave via LDS ----
    #pragma unroll
    for (int off = 32; off > 0; off >>= 1) {
        v_noobj   += __shfl_down(v_noobj, off);
        v_cnoobj  += __shfl_down(v_cnoobj, off);
        v_objconf += __shfl_down(v_objconf, off);
        v_xy      += __shfl_down(v_xy, off);
        v_wh      += __shfl_down(v_wh, off);
        v_clc     += __shfl_down(v_clc, off);
        v_cobj    += __shfl_down(v_cobj, off);
    }
    int wave = tid >> 6;
    int lane = tid & 63;
    if (lane == 0) {
        s_red[wave][0] = v_noobj;
        s_red[wave][1] = v_cnoobj;
        s_red[wave][2] = v_objconf;
        s_red[wave][3] = v_xy;
        s_red[wave][4] = v_wh;
        s_red[wave][5] = v_clc;
        s_red[wave][6] = v_cobj;
    }
    __syncthreads();
    if (tid == 0) {
        float* p = partials + (size_t)b * 8;
        #pragma unroll
        for (int k = 0; k < 7; ++k)
            p[k] = s_red[0][k] + s_red[1][k] + s_red[2][k] + s_red[3][k];
    }
}

// ---------------------------------------------------------------------------
// Kernel 2: deterministic fixed-order reduction of the 2048 partial rows,
// then apply the loss formula.
// ---------------------------------------------------------------------------
__global__ __launch_bounds__(256) void yolo_final_kernel(
        const float* __restrict__ partials,
        float* __restrict__ out)
{
    __shared__ float red[256][8];
    const int tid = threadIdx.x;
    float v[7] = {0.f, 0.f, 0.f, 0.f, 0.f, 0.f, 0.f};
    for (int r = tid; r < NBATCH; r += 256) {
        const float* p = partials + (size_t)r * 8;
        #pragma unroll
        for (int k = 0; k < 7; ++k) v[k] += p[k];
    }
    #pragma unroll
    for (int k = 0; k < 7; ++k) red[tid][k] = v[k];
    __syncthreads();
    for (int s = 128; s > 0; s >>= 1) {
        if (tid < s) {
            #pragma unroll
            for (int k = 0; k < 7; ++k) red[tid][k] += red[tid + s][k];
        }
        __syncthreads();
    }
    if (tid == 0) {
        float s_noobj  = red[0][0];
        float c_noobj  = red[0][1];
        float s_objconf = red[0][2];
        float s_xy     = red[0][3];
        float s_wh     = red[0][4];
        float s_clc    = red[0][5];
        float c_obj    = red[0][6];

        float n_noobj = 2.0f * c_noobj;          // both boxes per noobj cell
        float n_resp  = c_obj;                   // exactly one resp box / obj cell
        float noobj_loss   = s_noobj / n_noobj;
        float objconf_loss = s_objconf / n_resp;
        float loss_xy = s_xy / (n_resp * 2.0f);
        float loss_wh = s_wh / (n_resp * 2.0f);
        float loss_clc = s_clc / (c_obj * (float)NCLS);
        out[0] = 5.0f * (loss_xy + loss_wh) + objconf_loss
               + 0.5f * noobj_loss + loss_clc;
    }
}

extern "C" void kernel_launch(void* const* d_in, const int* in_sizes, int n_in,
                              void* d_out, int out_size, void* d_ws, size_t ws_size,
                              hipStream_t stream) {
    const float* pred = (const float*)d_in[0];
    const float* target = (const float*)d_in[1];
    float* partials = (float*)d_ws;   // 2048 * 8 f32 = 64 KiB, fully overwritten
    float* out = (float*)d_out;

    yolo_partial_kernel<<<NBATCH, 256, 0, stream>>>(pred, target, partials);
    yolo_final_kernel<<<1, 256, 0, stream>>>(partials, out);
}

// Round 2
// 23.567 us; speedup vs baseline: 1.8383x; 1.8383x over previous
//
#include <hip/hip_runtime.h>
#include <math.h>

#define NBATCH 2048
#define GS 14
#define NCELL (GS * GS)      // 196
#define NCH 30
#define NPRED (NCELL * NCH)  // 5880 floats per batch
#define MAXOBJ 20
#define NCLS 20

// ---------------------------------------------------------------------------
// Kernel 1: one block per batch element.
//  - float4-stage the 23.5 KB pred slab into linear LDS
//  - wave-parallel object phase: lane o handles object o; last-write-wins
//    resolved via key shuffles (an object wins (mi,cell) iff no LATER valid
//    object has the same key); class one-hots are a union -> atomicOr mask
//  - per-cell loss partials, wave shuffle reduce, 7 sums per block
// partials[b*8+k]: 0=s_noobj 1=c_noobj 2=s_objconf 3=s_xy 4=s_wh 5=s_clc 6=c_obj 7=0
// ---------------------------------------------------------------------------
__global__ __launch_bounds__(256) void yolo_partial_kernel(
        const float* __restrict__ pred,
        const float* __restrict__ target,
        float* __restrict__ partials)
{
    __shared__ float s_pred[NPRED];               // 23520 B, linear stride-30
    __shared__ float s_tgt[MAXOBJ * 5];           // 400 B
    __shared__ float s_box[2][NCELL][4];          // offx,offy,w,h (6272 B)
    __shared__ unsigned char s_flag[2][NCELL];
    __shared__ unsigned int s_clsmask[NCELL];
    __shared__ float s_red[4][8];

    const int b = blockIdx.x;
    const int tid = threadIdx.x;

    // ---- stage pred slab: 1470 float4, coalesced ----
    const float4* ps4 = (const float4*)(pred + (size_t)b * NPRED);
    float4* sp4 = (float4*)s_pred;
    #pragma unroll
    for (int k = 0; k < 6; ++k) {
        int i = tid + k * 256;
        if (i < NPRED / 4) sp4[i] = ps4[i];
    }
    // ---- stage target row: 100 floats = 25 float4 ----
    if (tid < 25)
        ((float4*)s_tgt)[tid] = ((const float4*)(target + (size_t)b * (MAXOBJ * 5)))[tid];
    // ---- zero per-cell target state ----
    if (tid < NCELL) {
        s_flag[0][tid] = 0;
        s_flag[1][tid] = 0;
        s_clsmask[tid] = 0u;
    }
    __syncthreads();

    // ---- wave-parallel object phase (wave 0 only) ----
    if (tid < 64) {
        const float fg = (float)GS;
        const int o = tid;
        bool valid = false;
        int key = 0x40000000 + tid;   // unique sentinel so invalid lanes never collide
        int cell = 0, mi = 0, cls = 0;
        float offx = 0.f, offy = 0.f, w = 0.f, h = 0.f;
        if (o < MAXOBJ) {
            float x1 = s_tgt[o * 5 + 0];
            float y1 = s_tgt[o * 5 + 1];
            float x2 = s_tgt[o * 5 + 2];
            float y2 = s_tgt[o * 5 + 3];
            float cf = s_tgt[o * 5 + 4];
            valid = (x1 + y1 + x2 + y2 + cf) != 0.0f;
            if (valid) {
                float cx = (x1 + x2) * 0.5f * fg;
                float cy = (y1 + y2) * 0.5f * fg;
                w = x2 - x1;
                h = y2 - y1;
                int gx = min(max((int)floorf(cx), 0), GS - 1);
                int gy = min(max((int)floorf(cy), 0), GS - 1);
                offx = cx - (float)gx;
                offy = cy - (float)gy;
                cell = gy * GS + gx;
                const float* pc = &s_pred[cell * NCH];

                float tcx = offx / fg, tcy = offy / fg;
                float tlx = tcx - 0.5f * w, tly = tcy - 0.5f * h;
                float trx = tcx + 0.5f * w, trY = tcy + 0.5f * h;
                float ta = (trx - tlx) * (trY - tly);

                float iou0, iou1;
                {
                    float px = pc[1] / fg, py = pc[2] / fg;
                    float pw = pc[3], ph = pc[4];
                    float plx = px - 0.5f * pw, ply = py - 0.5f * ph;
                    float prx = px + 0.5f * pw, prY = py + 0.5f * ph;
                    float ix = fmaxf(fminf(prx, trx) - fmaxf(plx, tlx), 0.f);
                    float iy = fmaxf(fminf(prY, trY) - fmaxf(ply, tly), 0.f);
                    float inter = ix * iy;
                    float a1 = (prx - plx) * (prY - ply);
                    iou0 = inter / (a1 + ta - inter);
                }
                {
                    float px = pc[6] / fg, py = pc[7] / fg;
                    float pw = pc[8], ph = pc[9];
                    float plx = px - 0.5f * pw, ply = py - 0.5f * ph;
                    float prx = px + 0.5f * pw, prY = py + 0.5f * ph;
                    float ix = fmaxf(fminf(prx, trx) - fmaxf(plx, tlx), 0.f);
                    float iy = fmaxf(fminf(prY, trY) - fmaxf(ply, tly), 0.f);
                    float inter = ix * iy;
                    float a1 = (prx - plx) * (prY - ply);
                    iou1 = inter / (a1 + ta - inter);
                }
                mi = (iou1 > iou0) ? 1 : 0;   // argmax, first-wins on tie
                cls = (int)cf;
                key = mi * NCELL + cell;
            }
        }
        // last-write-wins: lane o loses if any later valid lane shares its key
        bool win = valid;
        #pragma unroll
        for (int j = 0; j < MAXOBJ; ++j) {
            int kj = __shfl(key, j);
            if (j > o && kj == key) win = false;
        }
        if (win) {
            s_flag[mi][cell] = 1;
            s_box[mi][cell][0] = offx;
            s_box[mi][cell][1] = offy;
            s_box[mi][cell][2] = w;
            s_box[mi][cell][3] = h;
        }
        if (valid) atomicOr(&s_clsmask[cell], 1u << cls);
    }
    __syncthreads();

    // ---- per-cell loss partials (one cell per thread, tid<196) ----
    float v_noobj = 0.f, v_cnoobj = 0.f, v_objconf = 0.f;
    float v_xy = 0.f, v_wh = 0.f, v_clc = 0.f, v_cobj = 0.f;
    if (tid < NCELL) {
        const int cell = tid;
        const float* pc = &s_pred[cell * NCH];
        int f0 = s_flag[0][cell];
        int f1 = s_flag[1][cell];
        int nset = f0 + f1;
        if (nset == 0) {
            float c0 = pc[0];
            float c1 = pc[5];
            v_noobj = c0 * c0 + c1 * c1;
            v_cnoobj = 1.0f;
        } else if (nset == 1) {
            int k = f1;  // index of the set box
            float dconf = pc[k * 5 + 0] - 1.0f;
            v_objconf = dconf * dconf;
            float dx = pc[k * 5 + 1] - s_box[k][cell][0];
            float dy = pc[k * 5 + 2] - s_box[k][cell][1];
            v_xy = dx * dx + dy * dy;
            float sw = sqrtf(pc[k * 5 + 3]) - sqrtf(s_box[k][cell][2]);
            float sh = sqrtf(pc[k * 5 + 4]) - sqrtf(s_box[k][cell][3]);
            v_wh = sw * sw + sh * sh;
            unsigned int m = s_clsmask[cell];
            #pragma unroll
            for (int c = 0; c < NCLS; ++c) {
                float t = ((m >> c) & 1u) ? 1.0f : 0.0f;
                float d = pc[10 + c] - t;
                v_clc += d * d;
            }
            v_cobj = 1.0f;
        }
        // nset == 2: excluded from every loss term
    }

    // ---- wave shuffle reduce, then cross-wave via LDS ----
    #pragma unroll
    for (int off = 32; off > 0; off >>= 1) {
        v_noobj   += __shfl_down(v_noobj, off);
        v_cnoobj  += __shfl_down(v_cnoobj, off);
        v_objconf += __shfl_down(v_objconf, off);
        v_xy      += __shfl_down(v_xy, off);
        v_wh      += __shfl_down(v_wh, off);
        v_clc     += __shfl_down(v_clc, off);
        v_cobj    += __shfl_down(v_cobj, off);
    }
    int wave = tid >> 6;
    if ((tid & 63) == 0) {
        s_red[wave][0] = v_noobj;
        s_red[wave][1] = v_cnoobj;
        s_red[wave][2] = v_objconf;
        s_red[wave][3] = v_xy;
        s_red[wave][4] = v_wh;
        s_red[wave][5] = v_clc;
        s_red[wave][6] = v_cobj;
    }
    __syncthreads();
    if (tid == 0) {
        float* p = partials + (size_t)b * 8;
        #pragma unroll
        for (int k = 0; k < 7; ++k)
            p[k] = s_red[0][k] + s_red[1][k] + s_red[2][k] + s_red[3][k];
        p[7] = 0.0f;   // keep ws deterministic for kernel 2's vector read
    }
}

// ---------------------------------------------------------------------------
// Kernel 2: deterministic fixed-order reduction of the 2048 partial rows,
// then the final loss formula.
// ---------------------------------------------------------------------------
__global__ __launch_bounds__(256) void yolo_final_kernel(
        const float* __restrict__ partials,
        float* __restrict__ out)
{
    __shared__ float red[256][8];
    const int tid = threadIdx.x;
    float4 a0 = {0.f, 0.f, 0.f, 0.f};
    float4 a1 = {0.f, 0.f, 0.f, 0.f};
    for (int r = tid; r < NBATCH; r += 256) {
        const float4* p = (const float4*)(partials + (size_t)r * 8);
        float4 x0 = p[0];
        float4 x1 = p[1];
        a0.x += x0.x; a0.y += x0.y; a0.z += x0.z; a0.w += x0.w;
        a1.x += x1.x; a1.y += x1.y; a1.z += x1.z; a1.w += x1.w;
    }
    red[tid][0] = a0.x; red[tid][1] = a0.y; red[tid][2] = a0.z; red[tid][3] = a0.w;
    red[tid][4] = a1.x; red[tid][5] = a1.y; red[tid][6] = a1.z; red[tid][7] = a1.w;
    __syncthreads();
    for (int s = 128; s > 0; s >>= 1) {
        if (tid < s) {
            #pragma unroll
            for (int k = 0; k < 7; ++k) red[tid][k] += red[tid + s][k];
        }
        __syncthreads();
    }
    if (tid == 0) {
        float s_noobj   = red[0][0];
        float c_noobj   = red[0][1];
        float s_objconf = red[0][2];
        float s_xy      = red[0][3];
        float s_wh      = red[0][4];
        float s_clc     = red[0][5];
        float c_obj     = red[0][6];

        float n_noobj = 2.0f * c_noobj;      // both boxes of each noobj cell
        float n_resp  = c_obj;               // one responsible box per obj cell
        float noobj_loss   = s_noobj / n_noobj;
        float objconf_loss = s_objconf / n_resp;
        float loss_xy  = s_xy / (n_resp * 2.0f);
        float loss_wh  = s_wh / (n_resp * 2.0f);
        float loss_clc = s_clc / (c_obj * (float)NCLS);
        out[0] = 5.0f * (loss_xy + loss_wh) + objconf_loss
               + 0.5f * noobj_loss + loss_clc;
    }
}

extern "C" void kernel_launch(void* const* d_in, const int* in_sizes, int n_in,
                              void* d_out, int out_size, void* d_ws, size_t ws_size,
                              hipStream_t stream) {
    const float* pred = (const float*)d_in[0];
    const float* target = (const float*)d_in[1];
    float* partials = (float*)d_ws;   // 2048 * 8 f32 = 64 KiB, fully overwritten
    float* out = (float*)d_out;

    yolo_partial_kernel<<<NBATCH, 256, 0, stream>>>(pred, target, partials);
    yolo_final_kernel<<<1, 256, 0, stream>>>(partials, out);
}